// Round 1
// baseline (59.498 us; speedup 1.0000x reference)
//
#include <hip/hip_runtime.h>
#include <math.h>

#define HH 512
#define WW 1024
#define RR 5
#define KK 11
#define NMSH 3
#define TOPK 200
#define MAXC 16384

// ws layout (bytes):
// [0..63]   : meta ints: meta[0]=cnt, meta[1]=Mtop, meta[2]=anyv
// [64 ..)   : cv float[MAXC]
// [64+4*MAXC ..) : ci int[MAXC]
// [64+8*MAXC ..) : selx float[TOPK], sely float[TOPK]

__global__ __launch_bounds__(256) void vote_kernel(const float* __restrict__ cr,
                                                   float* __restrict__ vote) {
    __shared__ float sx[26][27];
    __shared__ float sy[26][27];
    const int tx = threadIdx.x & 15, ty = threadIdx.x >> 4;
    const int bx = blockIdx.x * 16, by = blockIdx.y * 16;
    const float* cr0 = cr;
    const float* cr1 = cr + HH * WW;
    for (int l = threadIdx.x; l < 26 * 26; l += 256) {
        int ly = l / 26, lx = l % 26;
        int gy = by + ly - RR, gx = bx + lx - RR;
        bool ok = (gy >= 0) && (gy < HH) && (gx >= 0) && (gx < WW);
        sx[ly][lx] = ok ? cr0[gy * WW + gx] : 0.0f;
        sy[ly][lx] = ok ? cr1[gy * WW + gx] : 0.0f;
    }
    __syncthreads();
    float err = 0.0f;
    // EXACT reference accumulation order: iy outer, ix inner, skip masked.
    #pragma unroll
    for (int iy = 0; iy < KK; ++iy) {
        #pragma unroll
        for (int ix = 0; ix < KK; ++ix) {
            const int ox = ix - RR, oy = iy - RR;
            if (ox * ox + oy * oy > RR * RR) continue;  // circle mask
            float rx = sx[ty + iy][tx + ix];
            float ry = sy[ty + iy][tx + ix];
            float dx = (float)ox - rx;
            float dy = (float)oy - ry;
            err += sqrtf(dx * dx + dy * dy);
        }
    }
    vote[(by + ty) * WW + (bx + tx)] = err / 81.0f + 1.0f;
}

__global__ __launch_bounds__(256) void nms_kernel(const float* __restrict__ vote,
                                                  float* __restrict__ cv, int* __restrict__ ci,
                                                  int* __restrict__ meta, float ct) {
    int pix = blockIdx.x * 256 + threadIdx.x;
    int y = pix >> 10, x = pix & (WW - 1);
    float v = vote[pix];
    float m = v;
    for (int dy = -NMSH; dy <= NMSH; ++dy) {
        int yy = y + dy;
        if (yy < 0 || yy >= HH) continue;
        for (int dx = -NMSH; dx <= NMSH; ++dx) {
            int xx = x + dx;
            if (xx < 0 || xx >= WW) continue;
            m = fminf(m, vote[yy * WW + xx]);
        }
    }
    // keep iff local min of 7x7 window AND strictly below CENTER_THRESH
    if (v == m && v < ct) {
        int s = atomicAdd(&meta[0], 1);
        if (s < MAXC) { cv[s] = v; ci[s] = pix; }
    }
}

__global__ __launch_bounds__(256) void select_kernel(const float* __restrict__ cv,
                                                     const int* __restrict__ ci,
                                                     int* __restrict__ meta,
                                                     float* __restrict__ selx,
                                                     float* __restrict__ sely,
                                                     float* __restrict__ out) {
    __shared__ float bv[256];
    __shared__ int bi[256];
    __shared__ int s_idx[TOPK];
    __shared__ float s_val[TOPK];
    const int tid = threadIdx.x;
    int M = meta[0];
    if (M > MAXC) M = MAXC;
    const int Mtop = (M < TOPK) ? M : TOPK;

    // k-th smallest by (val, idx) lexicographic = min over entries strictly
    // greater than the previously selected one (matches jax top_k tie-break).
    float lastv = -INFINITY;
    int lasti = -1;
    for (int k = 0; k < Mtop; ++k) {
        float bestv = INFINITY;
        int besti = 0x7fffffff;
        for (int j = tid; j < M; j += 256) {
            float v = cv[j];
            int i = ci[j];
            if (v > lastv || (v == lastv && i > lasti)) {
                if (v < bestv || (v == bestv && i < besti)) { bestv = v; besti = i; }
            }
        }
        bv[tid] = bestv; bi[tid] = besti;
        __syncthreads();
        for (int s = 128; s > 0; s >>= 1) {
            if (tid < s) {
                float ov = bv[tid + s]; int oi = bi[tid + s];
                if (ov < bv[tid] || (ov == bv[tid] && oi < bi[tid])) { bv[tid] = ov; bi[tid] = oi; }
            }
            __syncthreads();
        }
        lastv = bv[0]; lasti = bi[0];
        if (tid == 0) { s_val[k] = lastv; s_idx[k] = lasti; }
        __syncthreads();
    }

    if (tid == 0) {
        // fill remaining slots with the smallest non-candidate indices
        // (all non-candidates tie at -inf in top_k(-cand): ascending index)
        int cursor = 0;
        for (int k = Mtop; k < TOPK; ++k) {
            bool isc = true;
            while (isc) {
                isc = false;
                for (int j = 0; j < M; ++j) {
                    if (ci[j] == cursor) { isc = true; break; }
                }
                if (isc) cursor++;
            }
            s_idx[k] = cursor;
            s_val[k] = INFINITY;
            cursor++;
        }
        meta[1] = Mtop;
        meta[2] = (M > 0) ? 1 : 0;
    }
    __syncthreads();

    for (int k = tid; k < TOPK; k += 256) {
        int idx = s_idx[k];
        int cy = idx >> 10;          // idx / W
        int cx = idx & (WW - 1);     // idx % W
        out[HH * WW + 2 * k]     = (float)cy;
        out[HH * WW + 2 * k + 1] = (float)cx;
        bool valid = (k < Mtop);
        out[HH * WW + 2 * TOPK + k] = valid ? s_val[k] : 0.0f;
        selx[k] = (float)cx;
        sely[k] = (float)cy;
    }
}

__global__ __launch_bounds__(256) void inst_kernel(const float* __restrict__ fg,
                                                   const float* __restrict__ cr,
                                                   const float* __restrict__ selx,
                                                   const float* __restrict__ sely,
                                                   const int* __restrict__ meta,
                                                   float* __restrict__ out) {
    int pix = blockIdx.x * 256 + threadIdx.x;
    int y = pix >> 10, x = pix & (WW - 1);
    const int Mtop = meta[1];
    const int anyv = meta[2];
    float res = 0.0f;
    if (anyv && fg[pix] >= 0.5f) {
        float px = (float)(x + 1) - cr[pix];
        float py = (float)(y + 1) - cr[HH * WW + pix];
        float best = INFINITY;
        int bk = 0;
        for (int k = 0; k < Mtop; ++k) {
            float ddx = px - selx[k];
            float ddy = py - sely[k];
            float d = ddx * ddx + ddy * ddy;
            if (d < best) { best = d; bk = k; }  // strict < keeps first occurrence
        }
        res = (float)(bk + 1);
    }
    out[pix] = res;
}

extern "C" void kernel_launch(void* const* d_in, const int* in_sizes, int n_in,
                              void* d_out, int out_size, void* d_ws, size_t ws_size,
                              hipStream_t stream) {
    const float* fg = (const float*)d_in[0];
    const float* cr = (const float*)d_in[1];
    float* out = (float*)d_out;

    char* ws = (char*)d_ws;
    int* meta = (int*)ws;
    float* cv = (float*)(ws + 64);
    int* ci = (int*)(ws + 64 + 4 * MAXC);
    float* selx = (float*)(ws + 64 + 8 * MAXC);
    float* sely = selx + TOPK;

    // CENTER_THRESH = mean circle distance + 0.5 (double precision host calc;
    // ~1e-7 from the reference's fp32 value, margin to nearest vote is ~0.3)
    double s = 0.0;
    int n = 0;
    for (int iy = 0; iy < KK; ++iy)
        for (int ix = 0; ix < KK; ++ix) {
            double dx = ix - RR, dy = iy - RR;
            double d = sqrt(dx * dx + dy * dy);
            if (d <= (double)RR) { s += d; n++; }
        }
    float ct = (float)(s / n + 0.5);

    hipMemsetAsync(d_ws, 0, 64, stream);

    // vote map lives in out[0..H*W) (float); inst_kernel overwrites it last.
    dim3 vgrid(WW / 16, HH / 16);
    vote_kernel<<<vgrid, 256, 0, stream>>>(cr, out);
    nms_kernel<<<(HH * WW) / 256, 256, 0, stream>>>(out, cv, ci, meta, ct);
    select_kernel<<<1, 256, 0, stream>>>(cv, ci, meta, selx, sely, out);
    inst_kernel<<<(HH * WW) / 256, 256, 0, stream>>>(fg, cr, selx, sely, meta, out);
}